// Round 6
// baseline (227.747 us; speedup 1.0000x reference)
//
#include <hip/hip_runtime.h>
#include <hip/hip_bf16.h>
#include <stdint.h>

typedef __bf16 bf16x8 __attribute__((ext_vector_type(8)));
typedef __bf16 bf16x4 __attribute__((ext_vector_type(4)));
typedef float f32x4 __attribute__((ext_vector_type(4)));

#define DEV __device__ __forceinline__

DEV void gload_lds16(const void* g, void* l) {
  __builtin_amdgcn_global_load_lds((const __attribute__((address_space(1))) void*)g,
                                   (__attribute__((address_space(3))) void*)l, 16, 0, 0);
}

#define WAITV(n) asm volatile("s_waitcnt vmcnt(" #n ")" ::: "memory")
#define MFMA16x16(a, b, c) __builtin_amdgcn_mfma_f32_16x16x32_bf16(a, b, c, 0, 0, 0)

// ---------------- pack x: f32 -> bf16 ----------------
__global__ __launch_bounds__(256) void pack_x_kernel(const float* __restrict__ x,
                                                     __bf16* __restrict__ o, long n) {
  long i = ((long)blockIdx.x * 256 + threadIdx.x) * 4;
  const long stride = (long)gridDim.x * 256 * 4;
  for (; i < n; i += stride) {
    f32x4 v = *(const f32x4*)(x + i);
    bf16x4 b;
    b[0] = (__bf16)v[0]; b[1] = (__bf16)v[1]; b[2] = (__bf16)v[2]; b[3] = (__bf16)v[3];
    *(bf16x4*)(o + i) = b;
  }
}

// ---------------- pack W: [1024][1024] f32 -> Wt[e][d] bf16 (Wq scaled 1/32) ----------------
__global__ __launch_bounds__(256) void pack_w_kernel(const float* __restrict__ Wq,
                                                     const float* __restrict__ Wk,
                                                     const float* __restrict__ Wv,
                                                     __bf16* __restrict__ Wt) {
  const int w = blockIdx.z;
  const float* W = (w == 0) ? Wq : (w == 1) ? Wk : Wv;
  const float scale = (w == 0) ? 0.03125f : 1.0f;
  const int d0 = blockIdx.x * 64;
  const int e0 = blockIdx.y * 64;
  __shared__ __bf16 T[64][72];
  const int tid = threadIdx.x;
  const int r4 = tid >> 4;
  const int c4 = (tid & 15) * 4;
#pragma unroll
  for (int p = 0; p < 4; ++p) {
    int r = r4 + p * 16;
    f32x4 v = *(const f32x4*)(W + (long)(d0 + r) * 1024 + e0 + c4);
    T[r][c4 + 0] = (__bf16)(v[0] * scale);
    T[r][c4 + 1] = (__bf16)(v[1] * scale);
    T[r][c4 + 2] = (__bf16)(v[2] * scale);
    T[r][c4 + 3] = (__bf16)(v[3] * scale);
  }
  __syncthreads();
  const int e4 = tid >> 3;
  const int dd = (tid & 7) * 8;
#pragma unroll
  for (int p = 0; p < 2; ++p) {
    int e = e4 + p * 32;
    bf16x8 ov;
#pragma unroll
    for (int j = 0; j < 8; ++j) ov[j] = T[dd + j][e];
    *(bf16x8*)(Wt + (long)w * 1048576 + (long)(e0 + e) * 1024 + d0 + dd) = ov;
  }
}

// ---------------- pack bias: concat, bq scaled 1/32, stays f32 ----------------
__global__ __launch_bounds__(256) void pack_bias_kernel(const float* __restrict__ bq,
                                                        const float* __restrict__ bk,
                                                        const float* __restrict__ bv,
                                                        float* __restrict__ o) {
  int i = blockIdx.x * 256 + threadIdx.x;
  if (i < 1024) o[i] = bq[i] * 0.03125f;
  else if (i < 2048) o[i] = bk[i - 1024];
  else if (i < 3072) o[i] = bv[i - 2048];
}

// ------------- 8-phase GEMM (m201 discipline): C[M,N] = A[M,K] * B[N,K]^T (+bias) -----------
// BM=BN=256, 8 waves (2M x 4N), wave tile 128x64. Pipeline unit = K-slice of 32
// (A 16KB + B 16KB = 32KB), ring-3 units in LDS (96 KiB). Unit u stages unit u+2 into the
// buffer that went dead at the end of unit u-1 (race-free by construction). Per unit,
// 2 phases; each phase: {4-8 ds_read_b128, 2 global_load_lds} -> s_barrier ->
// lgkmcnt(0)+sched_barrier -> setprio(1), 16 MFMA, setprio(0) -> s_barrier. The reads
// drain while waves converge at the barrier (m201's latency-hiding trick). Boundary wait
// is counted vmcnt(4): covers loads issued ~2 units earlier -> free; never drains mid-loop.
// LDS layout is fragment-major: slot s (16B) at offset s*16, slot s <-> (row (s>>6)*16+(s&15),
// kchunk (s>>4)&3), so gload dests are linear AND every ds_read is 64 contiguous 16B lanes
// -> structurally conflict-free, no XOR swizzle needed.
// MODE 0: f32 out. MODE 1: bf16 out + bias.
template <int MODE>
__global__ __launch_bounds__(512, 1) void gemm8p_kernel(
    const __bf16* __restrict__ A, int lda,
    const __bf16* __restrict__ B, int ldb, long long bBatchStride, int bmShift,
    const float* __restrict__ bias,
    void* __restrict__ C, int ldc,
    int nTiles, int nu,
    int khA, int khB, long long khCBytes) {
  constexpr int UNITB = 32768;
  __shared__ __attribute__((aligned(128))) char lds[3 * UNITB];

  const int tid = threadIdx.x;
  const int lane = tid & 63;
  const int wid = tid >> 6;
  const int wm = wid >> 2, wn = wid & 3;  // 2M x 4N waves; wave tile 128x64
  const int lo = lane & 15, hi = lane >> 4;
  (void)lo; (void)hi;

  // bijective XCD swizzle (gridDim.x % 8 == 0 for all calls)
  const int cpx = gridDim.x >> 3;
  const int bid = blockIdx.x;
  const int swz = (bid & 7) * cpx + (bid >> 3);
  const int bm = swz / nTiles, bn = swz % nTiles;
  const int kh = blockIdx.y;

  const __bf16* Ab = A + (long long)kh * khA;
  const __bf16* Bb = B + (long long)(bm >> bmShift) * bBatchStride + (long long)kh * khB;

  // staging: per thread 4 gloads; slot s -> global (row, kchunk), LDS dest s*16 (linear)
  const __bf16* gsrc[4];
  int ldst[4];
#pragma unroll
  for (int l = 0; l < 4; ++l) {
    int s = (l & 1) * 512 + tid;
    int r = ((s >> 6) << 4) + (s & 15);
    int c = (s >> 4) & 3;
    if (l < 2) {
      gsrc[l] = Ab + (long long)(bm * 256 + r) * lda + c * 8;
      ldst[l] = s * 16;
    } else {
      gsrc[l] = Bb + (long long)(bn * 256 + r) * ldb + c * 8;
      ldst[l] = 16384 + s * 16;
    }
  }

  // fragment read offsets: frag g occupies bytes [g*1024, g*1024+1024), lane-linear
  const int aBase = (wm * 8) * 1024 + lane * 16;           // + mi*1024, mi in 0..7
  const int bBase = 16384 + (wn * 4) * 1024 + lane * 16;   // + ni*1024, ni in 0..3

  f32x4 acc[8][4] = {};

#define STAGE_ALL(uu)                                                          \
  do {                                                                         \
    char* sb_ = lds + ((uu) % 3) * UNITB;                                      \
    const long long ko_ = (long long)(uu) * 32;                                \
    _Pragma("unroll") for (int l = 0; l < 4; ++l)                              \
        gload_lds16(gsrc[l] + ko_, sb_ + ldst[l]);                             \
  } while (0)

  // prologue: stage units 0,1; wait unit 0 landed (unit 1's 4 loads stay in flight)
  STAGE_ALL(0);
  STAGE_ALL(1);
  WAITV(4);
  __builtin_amdgcn_s_barrier();
  __builtin_amdgcn_sched_barrier(0);

  for (int u = 0; u < nu; ++u) {
    const char* base = lds + (u % 3) * UNITB;
    char* sb = lds + ((u + 2) % 3) * UNITB;
    const long long ko = (long long)(u + 2) * 32;
    const bool st = (u + 2 < nu);
    bf16x8 bfrag[4], afrag[4];

    // ---- phase a: all B frags + A mi0-3; stage A-half of u+2 ----
#pragma unroll
    for (int ni = 0; ni < 4; ++ni) bfrag[ni] = *(const bf16x8*)(base + bBase + ni * 1024);
#pragma unroll
    for (int mi = 0; mi < 4; ++mi) afrag[mi] = *(const bf16x8*)(base + aBase + mi * 1024);
    if (st) { gload_lds16(gsrc[0] + ko, sb + ldst[0]); gload_lds16(gsrc[1] + ko, sb + ldst[1]); }
    __builtin_amdgcn_s_barrier();
    asm volatile("s_waitcnt lgkmcnt(0)" ::: "memory");
    __builtin_amdgcn_sched_barrier(0);
    __builtin_amdgcn_s_setprio(1);
#pragma unroll
    for (int mi = 0; mi < 4; ++mi)
#pragma unroll
      for (int ni = 0; ni < 4; ++ni)
        acc[mi][ni] = MFMA16x16(afrag[mi], bfrag[ni], acc[mi][ni]);
    __builtin_amdgcn_s_setprio(0);
    __builtin_amdgcn_s_barrier();

    // ---- phase b: A mi4-7 (B held in regs); stage B-half of u+2 ----
#pragma unroll
    for (int mi = 0; mi < 4; ++mi) afrag[mi] = *(const bf16x8*)(base + aBase + (mi + 4) * 1024);
    if (st) { gload_lds16(gsrc[2] + ko, sb + ldst[2]); gload_lds16(gsrc[3] + ko, sb + ldst[3]); }
    __builtin_amdgcn_s_barrier();
    asm volatile("s_waitcnt lgkmcnt(0)" ::: "memory");
    __builtin_amdgcn_sched_barrier(0);
    __builtin_amdgcn_s_setprio(1);
#pragma unroll
    for (int mi = 0; mi < 4; ++mi)
#pragma unroll
      for (int ni = 0; ni < 4; ++ni)
        acc[mi + 4][ni] = MFMA16x16(afrag[mi], bfrag[ni], acc[mi + 4][ni]);
    __builtin_amdgcn_s_setprio(0);

    // unit boundary: unit u+1 (staged during u-1) must be fully landed
    if (u + 1 < nu) {
      if (st) WAITV(4); else WAITV(0);
      __builtin_amdgcn_s_barrier();
      __builtin_amdgcn_sched_barrier(0);
    }
  }
#undef STAGE_ALL

  // epilogue: C/D map col=lane&15, row=(lane>>4)*4+j  [m89-verified]
  char* Cb = (char*)C + (long long)kh * khCBytes;
  const int lo2 = lane & 15, hi2 = lane >> 4;
  const long long row0 = (long long)bm * 256 + wm * 128 + hi2 * 4;
  const long long col0 = (long long)bn * 256 + wn * 64 + lo2;
#pragma unroll
  for (int ni = 0; ni < 4; ++ni) {
    const long long col = col0 + ni * 16;
    const float bvs = (MODE == 1) ? bias[col] : 0.0f;
#pragma unroll
    for (int mi = 0; mi < 8; ++mi) {
#pragma unroll
      for (int j = 0; j < 4; ++j) {
        float v = acc[mi][ni][j] + bvs;
        if (MODE == 1)
          ((__bf16*)Cb)[(row0 + mi * 16 + j) * ldc + col] = (__bf16)v;
        else
          ((float*)Cb)[(row0 + mi * 16 + j) * ldc + col] = v;
      }
    }
  }
}

// ---------------- transpose V (from QKV col block 2048..3071) -> Vt[b][e][t] ----------------
__global__ __launch_bounds__(256) void transpose_v_kernel(const __bf16* __restrict__ QKV,
                                                          __bf16* __restrict__ Vt) {
  const int t0 = blockIdx.x * 64;
  const int e0 = blockIdx.y * 64;
  const int b = blockIdx.z;
  __shared__ __bf16 T[64][72];
  const int tid = threadIdx.x;
  const int rr = tid >> 3;
  const int cc = (tid & 7) * 8;
  const __bf16* src = QKV + (long long)b * 2048 * 3072 + 2048;
#pragma unroll
  for (int p = 0; p < 2; ++p) {
    int t = rr + p * 32;
    bf16x8 v = *(const bf16x8*)(src + (long long)(t0 + t) * 3072 + e0 + cc);
#pragma unroll
    for (int j = 0; j < 8; ++j) T[t][cc + j] = v[j];
  }
  __syncthreads();
  __bf16* dst = Vt + (long long)b * 1024 * 2048;
#pragma unroll
  for (int p = 0; p < 2; ++p) {
    int e = rr + p * 32;
    bf16x8 ov;
#pragma unroll
    for (int j = 0; j < 8; ++j) ov[j] = T[cc + j][e];
    *(bf16x8*)(dst + (long long)(e0 + e) * 2048 + t0 + cc) = ov;
  }
}

// ---------------- row softmax in place: f32 row[2048] -> bf16 row (first half) ----------------
__global__ __launch_bounds__(256) void softmax_kernel(float* __restrict__ S) {
  const long long row = blockIdx.x;
  float* p = S + row * 2048;
  const int tid = threadIdx.x;
  const int lane = tid & 63, wid = tid >> 6;
  f32x4 v0 = *(const f32x4*)(p + tid * 8);
  f32x4 v1 = *(const f32x4*)(p + tid * 8 + 4);
  float xv[8] = {v0[0], v0[1], v0[2], v0[3], v1[0], v1[1], v1[2], v1[3]};
  float mx = xv[0];
#pragma unroll
  for (int j = 1; j < 8; ++j) mx = fmaxf(mx, xv[j]);
#pragma unroll
  for (int off = 32; off >= 1; off >>= 1) mx = fmaxf(mx, __shfl_xor(mx, off));
  __shared__ float red[8];
  if (lane == 0) red[wid] = mx;
  __syncthreads();
  mx = fmaxf(fmaxf(red[0], red[1]), fmaxf(red[2], red[3]));
  float e[8];
  float sum = 0.f;
#pragma unroll
  for (int j = 0; j < 8; ++j) {
    e[j] = __expf(xv[j] - mx);
    sum += e[j];
  }
#pragma unroll
  for (int off = 32; off >= 1; off >>= 1) sum += __shfl_xor(sum, off);
  if (lane == 0) red[4 + wid] = sum;
  __syncthreads();
  sum = red[4] + red[5] + red[6] + red[7];
  const float inv = 1.0f / sum;
  bf16x8 ov;
#pragma unroll
  for (int j = 0; j < 8; ++j) ov[j] = (__bf16)(e[j] * inv);
  *(bf16x8*)((__bf16*)p + tid * 8) = ov;
}

// ---------------- add split-K partials: out = p0 + p1 ----------------
__global__ __launch_bounds__(256) void add_kernel(const float* __restrict__ p0,
                                                  const float* __restrict__ p1,
                                                  float* __restrict__ o, long n) {
  long i = ((long)blockIdx.x * 256 + threadIdx.x) * 4;
  const long stride = (long)gridDim.x * 256 * 4;
  for (; i < n; i += stride) {
    f32x4 a = *(const f32x4*)(p0 + i);
    f32x4 b = *(const f32x4*)(p1 + i);
    *(f32x4*)(o + i) = a + b;
  }
}

extern "C" void kernel_launch(void* const* d_in, const int* in_sizes, int n_in,
                              void* d_out, int out_size, void* d_ws, size_t ws_size,
                              hipStream_t stream) {
  (void)in_sizes; (void)n_in; (void)out_size;
  const float* x  = (const float*)d_in[0];
  const float* Wq = (const float*)d_in[1];
  const float* bq = (const float*)d_in[2];
  const float* Wk = (const float*)d_in[3];
  const float* bk = (const float*)d_in[4];
  const float* Wv = (const float*)d_in[5];
  const float* bv = (const float*)d_in[6];
  float* out = (float*)d_out;
  char* ws = (char*)d_ws;
  if (ws_size < 157298688ULL) return;

  __bf16* x16  = (__bf16*)(ws + 0);          // 8192*1024*2      = 16,777,216
  __bf16* Wt   = (__bf16*)(ws + 16777216);   // 3072*1024*2      =  6,291,456
  float*  bqkv = (float*)(ws + 23068672);    // 3072*4           =     12,288
  __bf16* QKV  = (__bf16*)(ws + 23080960);   // 8192*3072*2      = 50,331,648
  __bf16* Vt   = (__bf16*)(ws + 73412608);   // 4*1024*2048*2    = 16,777,216
  float*  S    = (float*)(ws + 90189824);    // 4*2048*2048*4    = 67,108,864
  // split-K partials alias regions dead by GEMM3 time (x16/Wt/bias/QKV):
  float*  P0   = (float*)(ws + 0);           // 8192*1024*4      = 33,554,432
  float*  P1   = (float*)(ws + 33554432);    // 8192*1024*4      = 33,554,432

  pack_x_kernel<<<2048, 256, 0, stream>>>(x, x16, 8388608L);
  pack_w_kernel<<<dim3(16, 16, 3), 256, 0, stream>>>(Wq, Wk, Wv, Wt);
  pack_bias_kernel<<<12, 256, 0, stream>>>(bq, bk, bv, bqkv);

  // GEMM1: QKV[8192,3072] = x16 @ Wt^T + bias (bf16 out, Q cols pre-scaled by 1/32)
  gemm8p_kernel<1><<<dim3(384, 1), 512, 0, stream>>>(
      x16, 1024, Wt, 1024, 0LL, 30, bqkv, QKV, 3072, 12, 32, 0, 0, 0LL);

  // GEMM2: S[8192,2048] = Q @ K^T (f32); grid 256 = 1 full round
  gemm8p_kernel<0><<<dim3(256, 1), 512, 0, stream>>>(
      QKV, 3072, QKV + 1024, 3072, 6291456LL, 3, nullptr, S, 2048, 8, 32, 0, 0, 0LL);

  transpose_v_kernel<<<dim3(32, 16, 4), 256, 0, stream>>>(QKV, Vt);

  // softmax rows of S, write bf16 P in place
  softmax_kernel<<<8192, 256, 0, stream>>>(S);

  // GEMM3: out = P @ Vt^T, split-K=2 (blockIdx.y = kh); grid 128x2 = 256 blocks
  gemm8p_kernel<0><<<dim3(128, 2), 512, 0, stream>>>(
      (const __bf16*)S, 4096, Vt, 2048, 2097152LL, 3, nullptr, P0, 1024,
      4, 32, 1024, 1024, 33554432LL);

  add_kernel<<<2048, 256, 0, stream>>>(P0, P1, out, 8388608L);
}

// Round 7
// 166.859 us; speedup vs baseline: 1.3649x; 1.3649x over previous
//
#include <hip/hip_runtime.h>
#include <hip/hip_bf16.h>
#include <stdint.h>

typedef __bf16 bf16x8 __attribute__((ext_vector_type(8)));
typedef __bf16 bf16x4 __attribute__((ext_vector_type(4)));
typedef float f32x4 __attribute__((ext_vector_type(4)));

#define DEV __device__ __forceinline__

DEV void gload_lds16(const void* g, void* l) {
  __builtin_amdgcn_global_load_lds((const __attribute__((address_space(1))) void*)g,
                                   (__attribute__((address_space(3))) void*)l, 16, 0, 0);
}

#define WAITV0 asm volatile("s_waitcnt vmcnt(0)" ::: "memory")
#define MFMA16x16(a, b, c) __builtin_amdgcn_mfma_f32_16x16x32_bf16(a, b, c, 0, 0, 0)

// ---------------- pack x: f32 -> bf16 ----------------
__global__ __launch_bounds__(256) void pack_x_kernel(const float* __restrict__ x,
                                                     __bf16* __restrict__ o, long n) {
  long i = ((long)blockIdx.x * 256 + threadIdx.x) * 4;
  const long stride = (long)gridDim.x * 256 * 4;
  for (; i < n; i += stride) {
    f32x4 v = *(const f32x4*)(x + i);
    bf16x4 b;
    b[0] = (__bf16)v[0]; b[1] = (__bf16)v[1]; b[2] = (__bf16)v[2]; b[3] = (__bf16)v[3];
    *(bf16x4*)(o + i) = b;
  }
}

// ---------------- pack W: [1024][1024] f32 -> Wt[e][d] bf16 (Wq scaled 1/32) ----------------
__global__ __launch_bounds__(256) void pack_w_kernel(const float* __restrict__ Wq,
                                                     const float* __restrict__ Wk,
                                                     const float* __restrict__ Wv,
                                                     __bf16* __restrict__ Wt) {
  const int w = blockIdx.z;
  const float* W = (w == 0) ? Wq : (w == 1) ? Wk : Wv;
  const float scale = (w == 0) ? 0.03125f : 1.0f;
  const int d0 = blockIdx.x * 64;
  const int e0 = blockIdx.y * 64;
  __shared__ __bf16 T[64][72];
  const int tid = threadIdx.x;
  const int r4 = tid >> 4;
  const int c4 = (tid & 15) * 4;
#pragma unroll
  for (int p = 0; p < 4; ++p) {
    int r = r4 + p * 16;
    f32x4 v = *(const f32x4*)(W + (long)(d0 + r) * 1024 + e0 + c4);
    T[r][c4 + 0] = (__bf16)(v[0] * scale);
    T[r][c4 + 1] = (__bf16)(v[1] * scale);
    T[r][c4 + 2] = (__bf16)(v[2] * scale);
    T[r][c4 + 3] = (__bf16)(v[3] * scale);
  }
  __syncthreads();
  const int e4 = tid >> 3;
  const int dd = (tid & 7) * 8;
#pragma unroll
  for (int p = 0; p < 2; ++p) {
    int e = e4 + p * 32;
    bf16x8 ov;
#pragma unroll
    for (int j = 0; j < 8; ++j) ov[j] = T[dd + j][e];
    *(bf16x8*)(Wt + (long)w * 1048576 + (long)(e0 + e) * 1024 + d0 + dd) = ov;
  }
}

// ---------------- pack bias: concat, bq scaled 1/32, stays f32 ----------------
__global__ __launch_bounds__(256) void pack_bias_kernel(const float* __restrict__ bq,
                                                        const float* __restrict__ bk,
                                                        const float* __restrict__ bv,
                                                        float* __restrict__ o) {
  int i = blockIdx.x * 256 + threadIdx.x;
  if (i < 1024) o[i] = bq[i] * 0.03125f;
  else if (i < 2048) o[i] = bk[i - 1024];
  else if (i < 3072) o[i] = bv[i - 2048];
}

// ---------- GEMM: C[M,N] = A[M,K] * B[N,K]^T, 128x128 tile, ring-2 dbuf, 2 blocks/CU -------
// BK=64 (128B rows), 4 waves (2x2), wave 64x64 via 4x4 16x16x32 frags (m97-proven loop).
// Ring-2 staging: stage(t+1) into buf^1 issued at TOP of tile t -> end-of-tile vmcnt(0)
// waits on loads issued ~1500cy earlier (removes m97's single-buffer drain tax). One
// barrier per K-tile. LDS 64KB -> 2 blocks/CU; the other block's waves cover barrier
// stalls (m114 TLP). Frag reads compiler-scheduled (fine-grained lgkmcnt, m97 behavior).
// chunk^(row&7) both-sides swizzle: 0 bank conflicts measured (R1/R3/R4).
// MODE 0: f32 out (G3). MODE 1: bf16 out (G2->S). MODE 2: G1 (bias; Q/K row-major bf16,
// V cols written TRANSPOSED into vt[b][e][t]).
template <int MODE>
__global__ __launch_bounds__(256, 2) void gemm128_kernel(
    const __bf16* __restrict__ A, int lda,
    const __bf16* __restrict__ B, int ldb, long long bBatchStride, int bmShift,
    const float* __restrict__ bias,
    void* __restrict__ C, int ldc,
    __bf16* __restrict__ vt,
    int nTiles, int nt) {
  constexpr int TILEB = 16384;              // one operand tile: 128 rows x 128B
  __shared__ __attribute__((aligned(128))) char lds[2 * 2 * TILEB];  // [buf][A,B]

  const int tid = threadIdx.x;
  const int lane = tid & 63;
  const int wid = tid >> 6;
  const int wm = wid >> 1, wn = wid & 1;    // 2x2 waves; wave tile 64x64
  const int lo = lane & 15, hi = lane >> 4;

  // bijective XCD swizzle (gridDim.x % 8 == 0 for all calls)
  const int cpx = gridDim.x >> 3;
  const int bid = blockIdx.x;
  const int swz = (bid & 7) * cpx + (bid >> 3);
  const int bm = swz / nTiles, bn = swz % nTiles;

  const __bf16* Bb = B + (long long)(bm >> bmShift) * bBatchStride;

  // staging: 4 A-loads + 4 B-loads per thread per K-tile; slot s -> row r=s>>3, LDS chunk
  // s&7 (linear dest), global source chunk inverse-swizzled: c=(s&7)^(r&7)
  const __bf16* gA[4]; const __bf16* gB[4]; int lA[4];
#pragma unroll
  for (int l = 0; l < 4; ++l) {
    int s = l * 256 + tid, r = s >> 3;
    int c = (s & 7) ^ (r & 7);
    gA[l] = A + (long long)(bm * 128 + r) * lda + c * 8;
    gB[l] = Bb + (long long)(bn * 128 + r) * ldb + c * 8;
    lA[l] = s * 16;
  }

  // fragment read offsets: row = w?*64 + f*16 + lo; chunk = (ks*4+hi)^(lo&7)
  const int c0 = ((0 * 4 + hi) ^ (lo & 7)) << 4;
  const int c1 = ((1 * 4 + hi) ^ (lo & 7)) << 4;
  const int aBase = (wm * 64 + lo) * 128;
  const int bBase = TILEB + (wn * 64 + lo) * 128;

  f32x4 acc[4][4] = {};

#define STAGE(tt, buf)                                                \
  do {                                                                \
    const long long ko_ = (long long)(tt) * 64;                       \
    char* lb_ = lds + (buf) * (2 * TILEB);                            \
    _Pragma("unroll") for (int l = 0; l < 4; ++l) {                   \
      gload_lds16(gA[l] + ko_, lb_ + lA[l]);                          \
      gload_lds16(gB[l] + ko_, lb_ + TILEB + lA[l]);                  \
    }                                                                 \
  } while (0)

  // prologue
  STAGE(0, 0);
  WAITV0;
  __builtin_amdgcn_s_barrier();
  __builtin_amdgcn_sched_barrier(0);

  for (int t = 0; t < nt; ++t) {
    if (t + 1 < nt) STAGE(t + 1, (t + 1) & 1);   // early issue; lands during this tile
    const char* base = lds + (t & 1) * (2 * TILEB);

    bf16x8 av[4][2], bv[4][2];
#pragma unroll
    for (int f = 0; f < 4; ++f) {
      av[f][0] = *(const bf16x8*)(base + aBase + f * 16 * 128 + c0);
      av[f][1] = *(const bf16x8*)(base + aBase + f * 16 * 128 + c1);
      bv[f][0] = *(const bf16x8*)(base + bBase + f * 16 * 128 + c0);
      bv[f][1] = *(const bf16x8*)(base + bBase + f * 16 * 128 + c1);
    }
#pragma unroll
    for (int mi = 0; mi < 4; ++mi)
#pragma unroll
      for (int ni = 0; ni < 4; ++ni) {
        acc[mi][ni] = MFMA16x16(av[mi][0], bv[ni][0], acc[mi][ni]);
        acc[mi][ni] = MFMA16x16(av[mi][1], bv[ni][1], acc[mi][ni]);
      }

    if (t + 1 < nt) {
      WAITV0;  // waits only the 8 loads issued at top of this tile -> near-free
      __builtin_amdgcn_s_barrier();
      __builtin_amdgcn_sched_barrier(0);
    }
  }
#undef STAGE

  // epilogue: C/D map col=lane&15, row=(lane>>4)*4+j  [m89-verified]
  const long long row0 = (long long)bm * 128 + wm * 64 + hi * 4;
  const long long col0 = (long long)bn * 128 + wn * 64 + lo;

  if (MODE == 0) {
    float* Cf = (float*)C;
#pragma unroll
    for (int ni = 0; ni < 4; ++ni) {
      const long long col = col0 + ni * 16;
#pragma unroll
      for (int mi = 0; mi < 4; ++mi)
#pragma unroll
        for (int j = 0; j < 4; ++j)
          Cf[(row0 + mi * 16 + j) * ldc + col] = acc[mi][ni][j];
    }
  } else if (MODE == 1) {
    __bf16* Ch = (__bf16*)C;
#pragma unroll
    for (int ni = 0; ni < 4; ++ni) {
      const long long col = col0 + ni * 16;
#pragma unroll
      for (int mi = 0; mi < 4; ++mi)
#pragma unroll
        for (int j = 0; j < 4; ++j)
          Ch[(row0 + mi * 16 + j) * ldc + col] = (__bf16)acc[mi][ni][j];
    }
  } else {
    if (bn < 16) {
      // Q/K block: bf16 row-major + bias
      __bf16* Ch = (__bf16*)C;
#pragma unroll
      for (int ni = 0; ni < 4; ++ni) {
        const long long col = col0 + ni * 16;
        const float bvs = bias[col];
#pragma unroll
        for (int mi = 0; mi < 4; ++mi)
#pragma unroll
          for (int j = 0; j < 4; ++j)
            Ch[(row0 + mi * 16 + j) * ldc + col] = (__bf16)(acc[mi][ni][j] + bvs);
      }
    } else {
      // V block: write transposed into vt[b][e][t], bf16x4 along t (R5-verified logic)
      const int b = bm >> 4;
      __bf16* vtb = vt + (long long)b * 2097152;
      const int t0 = (bm & 15) * 128 + wm * 64 + hi * 4;
#pragma unroll
      for (int ni = 0; ni < 4; ++ni) {
        const long long e = (long long)(bn - 16) * 128 + wn * 64 + ni * 16 + lo;
        const float bvs = bias[2048 + e];
#pragma unroll
        for (int mi = 0; mi < 4; ++mi) {
          bf16x4 o;
#pragma unroll
          for (int j = 0; j < 4; ++j) o[j] = (__bf16)(acc[mi][ni][j] + bvs);
          *(bf16x4*)(vtb + e * 2048 + t0 + mi * 16) = o;
        }
      }
    }
  }
}

// ---------------- row softmax in place on bf16 S row [2048] ----------------
__global__ __launch_bounds__(256) void softmax_kernel(__bf16* __restrict__ S) {
  const long long row = blockIdx.x;
  __bf16* p = S + row * 2048;
  const int tid = threadIdx.x;
  const int lane = tid & 63, wid = tid >> 6;
  bf16x8 v = *(const bf16x8*)(p + tid * 8);
  float xv[8];
#pragma unroll
  for (int j = 0; j < 8; ++j) xv[j] = (float)v[j];
  float mx = xv[0];
#pragma unroll
  for (int j = 1; j < 8; ++j) mx = fmaxf(mx, xv[j]);
#pragma unroll
  for (int off = 32; off >= 1; off >>= 1) mx = fmaxf(mx, __shfl_xor(mx, off));
  __shared__ float red[8];
  if (lane == 0) red[wid] = mx;
  __syncthreads();
  mx = fmaxf(fmaxf(red[0], red[1]), fmaxf(red[2], red[3]));
  float e[8];
  float sum = 0.f;
#pragma unroll
  for (int j = 0; j < 8; ++j) {
    e[j] = __expf(xv[j] - mx);
    sum += e[j];
  }
#pragma unroll
  for (int off = 32; off >= 1; off >>= 1) sum += __shfl_xor(sum, off);
  if (lane == 0) red[4 + wid] = sum;
  __syncthreads();
  sum = red[4] + red[5] + red[6] + red[7];
  const float inv = 1.0f / sum;
  bf16x8 ov;
#pragma unroll
  for (int j = 0; j < 8; ++j) ov[j] = (__bf16)(e[j] * inv);
  *(bf16x8*)(p + tid * 8) = ov;
}

extern "C" void kernel_launch(void* const* d_in, const int* in_sizes, int n_in,
                              void* d_out, int out_size, void* d_ws, size_t ws_size,
                              hipStream_t stream) {
  (void)in_sizes; (void)n_in; (void)out_size;
  const float* x  = (const float*)d_in[0];
  const float* Wq = (const float*)d_in[1];
  const float* bq = (const float*)d_in[2];
  const float* Wk = (const float*)d_in[3];
  const float* bk = (const float*)d_in[4];
  const float* Wv = (const float*)d_in[5];
  const float* bv = (const float*)d_in[6];
  float* out = (float*)d_out;
  char* ws = (char*)d_ws;
  if (ws_size < 124000000ULL) return;

  __bf16* x16  = (__bf16*)(ws + 0);          // 8192*1024*2      = 16,777,216
  __bf16* Wt   = (__bf16*)(ws + 16777216);   // 3072*1024*2      =  6,291,456
  float*  bqkv = (float*)(ws + 23068672);    // 3072*4           =     12,288
  __bf16* QKV  = (__bf16*)(ws + 23080960);   // 8192*3072*2      = 50,331,648 (Q,K cols used)
  __bf16* Vt   = (__bf16*)(ws + 73412608);   // 4*1024*2048*2    = 16,777,216
  __bf16* S    = (__bf16*)(ws + 90189824);   // 8192*2048*2      = 33,554,432

  pack_x_kernel<<<2048, 256, 0, stream>>>(x, x16, 8388608L);
  pack_w_kernel<<<dim3(16, 16, 3), 256, 0, stream>>>(Wq, Wk, Wv, Wt);
  pack_bias_kernel<<<12, 256, 0, stream>>>(bq, bk, bv, bqkv);

  // GEMM1: QKV = x16 @ Wt^T + bias; Q/K row-major bf16, V transposed into Vt.
  // grid 64x24 = 1536 blocks (6 rounds at 2 blocks/CU)
  gemm128_kernel<2><<<dim3(1536), 256, 0, stream>>>(
      x16, 1024, Wt, 1024, 0LL, 30, bqkv, QKV, 3072, Vt, 24, 16);

  // GEMM2: S[8192,2048] = Q @ K^T (bf16 out); grid 64x16 = 1024
  gemm128_kernel<1><<<dim3(1024), 256, 0, stream>>>(
      QKV, 3072, QKV + 1024, 3072, 6291456LL, 4, nullptr, S, 2048, nullptr, 16, 16);

  // softmax rows of S in place (bf16)
  softmax_kernel<<<8192, 256, 0, stream>>>(S);

  // GEMM3: out[8192,1024] = P @ Vt^T (f32 out); grid 64x8 = 512
  gemm128_kernel<0><<<dim3(512), 256, 0, stream>>>(
      S, 2048, Vt, 2048, 2097152LL, 4, nullptr, out, 1024, nullptr, 8, 32);
}